// Round 3
// baseline (446.546 us; speedup 1.0000x reference)
//
#include <hip/hip_runtime.h>

// CalcSpixelFeats R22. Base = R21 (445us, fused kernel 370us).
// R21 post-mortem: 187 cycles per wave-level LDS atomic == LDS LATENCY, with
// VALUBusy 1% and zero bank conflicts -> HIP atomicAdd on __shared__ float is
// serializing one LDS round-trip per op (rtn form + dest-reg recycling forces
// s_waitcnt per atomic at VGPR_Count=36).
// R22: identical structure, but bin updates are inline-asm ds_add_f32
// (NO-RETURN) -> no dest VGPR, no waitcnt, fully pipelined fire-and-forget.
// LDS address = (unsigned)(uintptr_t)&bins[x]: the shared aperture on gfx9+
// is 2^32-aligned (SRC_SHARED_BASE supplies only the high 32 bits), so the
// low 32 bits of a flat LDS pointer ARE the LDS byte offset.
// Bin stride 33 (odd) keeps bank = (bin + c) & 31 -> full 32-bank spread
// (R21 counters confirmed: SQ_LDS_BANK_CONFLICT == 0).

#define CCH  32         // channels, fixed by problem
#define TPB  512        // 1 px/thread
#define KMAX 256        // superpixel count, fixed by problem
#define BSTR 33         // bin stride in floats (32 ch + wsum), odd for banks

__global__ __launch_bounds__(TPB, 4) void spx_fused_kernel(
    const float* __restrict__ pf,      // [B][C][P]
    const float* __restrict__ assoc,   // [B][9][P]
    const int*   __restrict__ idxmap,  // [B][P]
    const int*   __restrict__ nw_p,
    const int*   __restrict__ nh_p,
    float*       __restrict__ fsum,    // [B*K][CCH+1]
    int P, int K, int bpb)             // bpb = P / TPB
{
    __shared__ float bins[KMAX * BSTR];   // 33.8 KB

    const int b   = blockIdx.x / bpb;
    const int blk = blockIdx.x - b * bpb;
    const int tid = threadIdx.x;
    const int p   = blk * TPB + tid;   // pixel within batch (1 px/thread)

    // zero the bin table (17 floats/thread)
    for (int i = tid; i < KMAX * BSTR; i += TPB) bins[i] = 0.f;

    const int*   ix_b = idxmap + (size_t)b * P;
    const float* pf_b = pf     + (size_t)b * CCH * P;
    const float* as_b = assoc  + (size_t)b * 9 * P;

    // coalesced loads, all independent -> deep MLP while bins zero
    const int idx = ix_b[p];
    float f[CCH];
#pragma unroll
    for (int c = 0; c < CCH; ++c) f[c] = pf_b[(size_t)c * P + p];
    float wv[9];
#pragma unroll
    for (int j = 0; j < 9; ++j) wv[j] = as_b[(size_t)j * P + p];

    const int nw = nw_p[0], nh = nh_p[0];
    const int iy  = idx / nw;
    const int ixx = idx - iy * nw;

    __syncthreads();   // bins zeroed before any ds_add

#pragma unroll
    for (int j = 0; j < 9; ++j) {
        const int ty = iy + j / 3 - 1;
        const int tx = ixx + j % 3 - 1;
        if (tx >= 0 && tx < nw && ty >= 0 && ty < nh) {
            const float w = wv[j];
            // LDS byte address of this target bin (flat->LDS truncation)
            unsigned a = (unsigned)(uintptr_t)&bins[(ty * nw + tx) * BSTR];
#pragma unroll
            for (int c = 0; c < CCH; ++c) {
                const float v = w * f[c];
                asm volatile("ds_add_f32 %0, %1"
                             :: "v"(a), "v"(v) : "memory");
                a += 4u;
            }
            asm volatile("ds_add_f32 %0, %1"
                         :: "v"(a), "v"(w) : "memory");   // wsum
        }
    }

    __syncthreads();   // compiler emits lgkmcnt(0) before barrier ->
                       // all ds_add drained before the flush reads

    // flush block partials: 256 bins x 33 cols -> coalesced fire-and-forget
    // global fp atomics (value unused -> no-rtn global_atomic_add_f32)
    float* fs_b = fsum + (size_t)b * K * (CCH + 1);
    for (int i = tid; i < KMAX * (CCH + 1); i += TPB) {
        const int bin = i / (CCH + 1);
        const int cc  = i - bin * (CCH + 1);
        unsafeAtomicAdd(&fs_b[bin * (CCH + 1) + cc], bins[bin * BSTR + cc]);
    }
}

// Trivial finalize: one thread per output element (b,c,k), k fastest ->
// coalesced writes; fsum reads hit L2 (135 KB). Separate dispatch gives the
// device-wide visibility barrier for the atomics (kernel-boundary coherence).
__global__ __launch_bounds__(256) void spx_finalize_kernel(
    const float* __restrict__ fsum,  // [B*K][CCH+1]
    float*       __restrict__ out,   // [B][C][K]
    int K, int total)
{
    const int gid = blockIdx.x * 256 + threadIdx.x;
    if (gid >= total) return;
    const int k = gid % K;
    const int c = (gid / K) % CCH;
    const int b = gid / (K * CCH);
    const float* f = fsum + (size_t)(b * K + k) * (CCH + 1);
    const float W = f[CCH];
    out[gid] = (W > 1e-16f) ? (f[c] / W) : 0.f;
}

extern "C" void kernel_launch(void* const* d_in, const int* in_sizes, int n_in,
                              void* d_out, int out_size, void* d_ws, size_t ws_size,
                              hipStream_t stream) {
    const float* pf     = (const float*)d_in[0];
    const float* assoc  = (const float*)d_in[1];
    const int*   idxmap = (const int*)d_in[2];
    const int*   nw_p   = (const int*)d_in[3];
    const int*   nh_p   = (const int*)d_in[4];
    float* out = (float*)d_out;

    const int BP = in_sizes[2];          // B*P = 262144
    const int B  = 4;                    // fixed by reference setup
    const int P  = BP / B;               // 65536
    const int K  = out_size / (B * CCH); // 256 (== KMAX)

    // ws: fsum [B*K][33] only
    const size_t fsum_bytes = (size_t)B * K * (CCH + 1) * sizeof(float);
    float* fsum = (float*)d_ws;

    hipMemsetAsync(fsum, 0, fsum_bytes, stream);

    const int bpb = P / TPB;             // 128 blocks per batch
    spx_fused_kernel<<<B * bpb, TPB, 0, stream>>>(
        pf, assoc, idxmap, nw_p, nh_p, fsum, P, K, bpb);

    const int total = B * K * CCH;
    spx_finalize_kernel<<<(total + 255) / 256, 256, 0, stream>>>(
        fsum, out, K, total);
}

// Round 4
// 151.529 us; speedup vs baseline: 2.9469x; 2.9469x over previous
//
#include <hip/hip_runtime.h>

// CalcSpixelFeats R23. Base = R22 (446us; fused LDS-atomic kernel 370us).
// R22 post-mortem: LDS f32 atomics retire ~1 lane / 3 cy / CU, serialized
// (73.4M lane atomics * 3cy / 256 CU = 358us ~= measured 370; bank conflicts
// 0 -> it's the atomic ALU, not the crossbar). Scatter-accumulate via LDS
// atomics is dead at 297 atomics/px.
// R23: the op IS a GEMM. fsum[k,c] = sum_p G[k,p] * F[p,c], G = scatter
// matrix (9 distinct bins per pixel -> collision-free plain LDS writes, ZERO
// atomics). Dense work = 256k x 48c x 262144p = 6.4 GFLOP -> MFMA peanuts.
// Per 64-px chunk: scatter w (bf16) directly into mfma_f32_16x16x32_bf16
// A-fragment layout (A: row=lane&15, k=(lane>>4)*8+elem), stage features into
// B-fragment layout (B: col=lane&15, k same grouping), ones-channel at c=32
// gives wsum from the same MFMA. C/D layout = m89-verified
// (col=lane&15, row=(lane>>4)*4+reg). MFMA via inline asm (builtin signature
// ambiguity avoided); acc in VGPRs, one global-atomic flush per block.

#define CCH  32
#define KMAX 256
#define FST  (CCH + 1)     // fsum stride

typedef __attribute__((ext_vector_type(4))) int   int4v;
typedef __attribute__((ext_vector_type(4))) float f32x4;

__device__ __forceinline__ unsigned pack_bf16(float a, float b) {
    unsigned ua = __float_as_uint(a);
    unsigned ub = __float_as_uint(b);
    ua = (ua + 0x7FFFu + ((ua >> 16) & 1u)) >> 16;   // RNE
    ub = (ub + 0x7FFFu + ((ub >> 16) & 1u)) >> 16;
    return ua | (ub << 16);
}
__device__ __forceinline__ unsigned short bf16_1(float a) {
    unsigned ua = __float_as_uint(a);
    return (unsigned short)((ua + 0x7FFFu + ((ua >> 16) & 1u)) >> 16);
}

// A-fragment slot for element A[t][p] (t = bin row 0..255, p = pixel 0..63):
//   region = (t>>4)*2 + (p>>5), q = p&31, lane = (t&15) + 16*(q>>3), elem=q&7
// B-fragment slot for element B[p][c]: region = (c>>4)*2 + (p>>5),
//   lane = (c&15) + 16*(q>>3), elem = q&7.  (regions are 64 lanes x 16 B)

__global__ __launch_bounds__(256, 2) void spx_mfma_kernel(
    const float* __restrict__ pf,      // [B][C][P]
    const float* __restrict__ assoc,   // [B][9][P]
    const int*   __restrict__ idxmap,  // [B][P]
    const int*   __restrict__ nw_p,
    const int*   __restrict__ nh_p,
    float*       __restrict__ fsum,    // [B*K][FST]
    int P, int K, int cpb, int bpb)    // chunks/block, blocks/batch
{
    __shared__ __align__(16) short lsA[16 * 2 * 64 * 8];  // 32 KB
    __shared__ __align__(16) short lsB[6 * 64 * 8];       // 6 KB

    const int tid  = threadIdx.x;
    const int wave = tid >> 6;
    const int lane = tid & 63;
    const int b    = blockIdx.x / bpb;
    const int blkb = blockIdx.x - b * bpb;

    const int nw = nw_p[0], nh = nh_p[0];

    // static ones-region ct=2 (regions 4,5): B[p][32]=1, B[p][33..47]=0
    if (tid < 128) {
        const int reg = 4 + (tid >> 6);
        const int ln  = tid & 63;
        uint4 v = ((ln & 15) == 0)
            ? make_uint4(0x3F803F80u, 0x3F803F80u, 0x3F803F80u, 0x3F803F80u)
            : make_uint4(0u, 0u, 0u, 0u);
        *(uint4*)&lsB[(reg * 64 + ln) * 8] = v;
    }

    const int*   ix_b = idxmap + (size_t)b * P;
    const float* pf_b = pf     + (size_t)b * CCH * P;
    const float* as_b = assoc  + (size_t)b * 9 * P;

    f32x4 acc[4][3];
#pragma unroll
    for (int i = 0; i < 4; ++i)
#pragma unroll
        for (int j = 0; j < 3; ++j) acc[i][j] = f32x4{0.f, 0.f, 0.f, 0.f};

    const int grp = tid >> 6;   // j-group for scatter
    const int pl  = tid & 63;   // scatter pixel
    const int pp  = tid & 31;   // pixel-pair index for F staging
    const int cg  = tid >> 5;   // channel group 0..7

    for (int ch = 0; ch < cpb; ++ch) {
        const int p0 = (blkb * cpb + ch) * 64;

        // zero the A-fragment table (8 x uint4 per thread = 32 KB)
#pragma unroll
        for (int i = 0; i < 8; ++i)
            *(uint4*)&lsA[(tid + 256 * i) * 8] = make_uint4(0u, 0u, 0u, 0u);

        // global loads (issue before the barrier; drained at s_barrier)
        const int idx = ix_b[p0 + pl];
        float wv[3];
        int   jv[3];
#pragma unroll
        for (int wi = 0; wi < 3; ++wi) {
            const int j = grp + 4 * wi;
            jv[wi] = j;
            wv[wi] = (j < 9) ? as_b[(size_t)j * P + p0 + pl] : 0.f;
        }
        float2 fv[4];
#pragma unroll
        for (int ci = 0; ci < 4; ++ci) {
            const int c = cg + 8 * ci;
            fv[ci] = *(const float2*)&pf_b[(size_t)c * P + p0 + 2 * pp];
        }

        __syncthreads();   // zeroing complete

        // scatter A: bf16(w) -> slot (tbin, pl). 9 distinct bins per pixel
        // -> collision-free plain ds_write_b16, NO atomics.
        const int iy  = idx / nw;
        const int ixx = idx - iy * nw;
        const int q   = pl & 31;
        const int ps_ = pl >> 5;
#pragma unroll
        for (int wi = 0; wi < 3; ++wi) {
            const int j = jv[wi];
            if (j >= 9) continue;
            const int ty = iy + j / 3 - 1;
            const int tx = ixx + j % 3 - 1;
            if (tx < 0 || tx >= nw || ty < 0 || ty >= nh) continue;
            const int t   = ty * nw + tx;
            const int off = ((((t >> 4) * 2 + ps_) * 64
                              + (t & 15) + ((q >> 3) << 4)) * 8) + (q & 7);
            lsA[off] = (short)bf16_1(wv[wi]);
        }

        // stage B: feature pairs (k=p contiguous per lane -> b32 writes)
#pragma unroll
        for (int ci = 0; ci < 4; ++ci) {
            const int c  = cg + 8 * ci;
            const int p2 = 2 * pp;              // even -> same elem group
            const int q2 = p2 & 31;
            const int off = ((((c >> 4) * 2 + (p2 >> 5)) * 64
                              + (c & 15) + ((q2 >> 3) << 4)) * 8) + (q2 & 7);
            *(unsigned*)&lsB[off] = pack_bf16(fv[ci].x, fv[ci].y);
        }

        __syncthreads();   // fragments staged

        // MFMA: wave owns k-tiles 4w..4w+3; 3 c-tiles; 2 p-subtiles
#pragma unroll
        for (int ps = 0; ps < 2; ++ps) {
            int4v bfr[3];
#pragma unroll
            for (int ct = 0; ct < 3; ++ct)
                bfr[ct] = *(int4v*)&lsB[((ct * 2 + ps) * 64 + lane) * 8];
#pragma unroll
            for (int ktl = 0; ktl < 4; ++ktl) {
                const int kt = wave * 4 + ktl;
                int4v af = *(int4v*)&lsA[((kt * 2 + ps) * 64 + lane) * 8];
#pragma unroll
                for (int ct = 0; ct < 3; ++ct) {
                    asm("v_mfma_f32_16x16x32_bf16 %0, %1, %2, %0"
                        : "+v"(acc[ktl][ct])
                        : "v"(af), "v"(bfr[ct]));
                }
            }
        }

        __syncthreads();   // frags consumed; next iter may re-zero
    }

    // MFMA -> VALU read hazard guard before the flush reads acc
    asm volatile("s_nop 7\n\ts_nop 7");

    // flush: D[k][c], k = kt*16 + (lane>>4)*4 + i, c = ct*16 + (lane&15)
    float* fs_b = fsum + (size_t)b * K * FST;
    const int col  = lane & 15;
    const int rw0  = (lane >> 4) * 4;
#pragma unroll
    for (int ktl = 0; ktl < 4; ++ktl) {
        const int kt = wave * 4 + ktl;
#pragma unroll
        for (int ct = 0; ct < 3; ++ct) {
            const int c = ct * 16 + col;
            if (c > CCH) continue;      // ct=2: only col 0 (wsum) is real
#pragma unroll
            for (int i = 0; i < 4; ++i) {
                const int k = kt * 16 + rw0 + i;
                unsafeAtomicAdd(&fs_b[(size_t)k * FST + c], acc[ktl][ct][i]);
            }
        }
    }
}

// Trivial finalize: one thread per output element (b,c,k), k fastest ->
// coalesced writes; fsum reads hit L2 (135 KB).
__global__ __launch_bounds__(256) void spx_finalize_kernel(
    const float* __restrict__ fsum,  // [B*K][FST]
    float*       __restrict__ out,   // [B][C][K]
    int K, int total)
{
    const int gid = blockIdx.x * 256 + threadIdx.x;
    if (gid >= total) return;
    const int k = gid % K;
    const int c = (gid / K) % CCH;
    const int b = gid / (K * CCH);
    const float* f = fsum + (size_t)(b * K + k) * FST;
    const float W = f[CCH];
    out[gid] = (W > 1e-16f) ? (f[c] / W) : 0.f;
}

extern "C" void kernel_launch(void* const* d_in, const int* in_sizes, int n_in,
                              void* d_out, int out_size, void* d_ws, size_t ws_size,
                              hipStream_t stream) {
    const float* pf     = (const float*)d_in[0];
    const float* assoc  = (const float*)d_in[1];
    const int*   idxmap = (const int*)d_in[2];
    const int*   nw_p   = (const int*)d_in[3];
    const int*   nh_p   = (const int*)d_in[4];
    float* out = (float*)d_out;

    const int BP = in_sizes[2];          // B*P = 262144
    const int B  = 4;                    // fixed by reference setup
    const int P  = BP / B;               // 65536
    const int K  = out_size / (B * CCH); // 256 (== KMAX)

    // ws: fsum [B*K][33] only
    const size_t fsum_bytes = (size_t)B * K * FST * sizeof(float);
    float* fsum = (float*)d_ws;

    hipMemsetAsync(fsum, 0, fsum_bytes, stream);

    const int bpb = 128;                 // blocks per batch
    const int cpb = (P / 64) / bpb;      // 8 chunks of 64 px per block
    spx_mfma_kernel<<<B * bpb, 256, 0, stream>>>(
        pf, assoc, idxmap, nw_p, nh_p, fsum, P, K, cpb, bpb);

    const int total = B * K * CCH;
    spx_finalize_kernel<<<(total + 255) / 256, 256, 0, stream>>>(
        fsum, out, K, total);
}